// Round 7
// baseline (148.676 us; speedup 1.0000x reference)
//
#include <hip/hip_runtime.h>
#include <stdint.h>

typedef unsigned long long u64;

#define KCAND 9
#define BATCH 16
#define NPRED 30000
#define NGT   64
#define SUBN  3750          // every-8th subsample per image
#define CHUNK 1024          // elements per collect-block
#define NCH   30            // 30*1024 = 30720 >= 30000
#define CAP   1024          // survivor buffer per row
#define INITKEY 0x7F800000FFFFFFFFULL
#define FINF __uint_as_float(0x7F800000u)

__device__ __forceinline__ float rl_f(float v, int l) {
    return __uint_as_float((unsigned)__builtin_amdgcn_readlane((int)__float_as_uint(v), l));
}

// ---------------- kernel 1: compact xy + subsample ----------------
__global__ __launch_bounds__(256) void compact_k(
    const float* __restrict__ pred, float2* __restrict__ xy, float2* __restrict__ sub)
{
    int e = blockIdx.x * 256 + threadIdx.x;
    if (e < BATCH * NPRED) {
        float4 p = ((const float4*)pred)[e];
        xy[e] = make_float2(p.x, p.y);
        int b = e / NPRED;
        int i = e - b * NPRED;
        if ((i & 7) == 0) sub[b * SUBN + (i >> 3)] = make_float2(p.x, p.y);
    }
}

// ---------------- kernel 2: conservative per-row threshold ----------------
// T[row] = 9th-smallest of 64 lane-mins over the row's 3750-elem subsample.
// Subsample 9th-order-stat >= full 9th; 9th-lane-min >= subsample 9th  => T >= d9.
__global__ __launch_bounds__(256) void thresh_k(
    const float2* __restrict__ sub, const float* __restrict__ gt, float* __restrict__ T)
{
#pragma clang fp contract(off)
    const int lane = threadIdx.x & 63;
    const int wvid = threadIdx.x >> 6;
    const int row  = blockIdx.x * 4 + wvid;
    const int b    = row >> 6;

    const float gcx = gt[row * 4 + 0], gcy = gt[row * 4 + 1];
    const float2* sb = sub + b * SUBN;

    float lmin = FINF;
#pragma unroll 4
    for (int k = lane; k < SUBN; k += 64) {
        float2 p = sb[k];
        float dx = __fsub_rn(gcx, p.x);
        float dy = __fsub_rn(gcy, p.y);
        float d  = __fadd_rn(__fmul_rn(dx, dx), __fmul_rn(dy, dy));
        lmin = fminf(lmin, d);
    }
    // bitonic sort 64 lane values ascending; lane 8 = 9th smallest
    float x = lmin;
#pragma unroll
    for (int k = 2; k <= 64; k <<= 1) {
#pragma unroll
        for (int j = k >> 1; j >= 1; j >>= 1) {
            float o = __shfl_xor(x, j, 64);
            bool keepmin = (((lane & k) == 0) == ((lane & j) == 0));
            x = keepmin ? fminf(x, o) : fmaxf(x, o);
        }
    }
    if (lane == 8) T[row] = x;
}

// ---------------- kernel 3: collect survivors (each element read ONCE) ----------------
__global__ __launch_bounds__(256, 4) void collect_k(
    const float2* __restrict__ xy, const float* __restrict__ gt,
    const float* __restrict__ T, unsigned* __restrict__ cnt, u64* __restrict__ surv)
{
#pragma clang fp contract(off)
    const int lane = threadIdx.x & 63;
    const int wvid = threadIdx.x >> 6;
    const int b = blockIdx.x & 15;      // consecutive blocks -> different images (XCD spread)
    const int c = blockIdx.x >> 4;      // chunk 0..29
    const int rowbase = b * NGT;

    // lane-resident GT data: lane l holds GT l's center + threshold
    float gx_v = gt[(rowbase + lane) * 4 + 0];
    float gy_v = gt[(rowbase + lane) * 4 + 1];
    float Tv   = T[rowbase + lane];

    // 4 elements per lane, contiguous: coalesced 2x float4
    const int i0 = c * CHUNK + wvid * 256 + lane * 4;
    const float4* xb4 = (const float4*)(xy + (size_t)b * NPRED);
    const int f0 = i0 >> 1;
    float4 A = xb4[f0 < NPRED / 2 ? f0 : NPRED / 2 - 1];
    float4 Bq = xb4[f0 + 1 < NPRED / 2 ? f0 + 1 : NPRED / 2 - 1];
    float ex[4] = {A.x, A.z, Bq.x, Bq.z};
    float ey[4] = {A.y, A.w, Bq.y, Bq.w};
#pragma unroll
    for (int j = 0; j < 4; ++j)
        if (i0 + j >= NPRED) { ex[j] = FINF; ey[j] = FINF; }  // d2 -> +inf, never passes

    const u64 below = ((u64)1 << lane) - 1;

    for (int g = 0; g < NGT; ++g) {
        const float gcx = rl_f(gx_v, g);
        const float gcy = rl_f(gy_v, g);
        const float Tg  = rl_f(Tv, g);

        float d2[4]; bool p[4];
#pragma unroll
        for (int j = 0; j < 4; ++j) {
            float dx = __fsub_rn(gcx, ex[j]);
            float dy = __fsub_rn(gcy, ey[j]);
            d2[j] = __fadd_rn(__fmul_rn(dx, dx), __fmul_rn(dy, dy));
            p[j] = d2[j] <= Tg;
        }
        if (__ballot(p[0] | p[1] | p[2] | p[3]) == 0ULL) continue;

        u64 b0 = __ballot(p[0]), b1 = __ballot(p[1]), b2 = __ballot(p[2]), b3 = __ballot(p[3]);
        int tot = __popcll(b0) + __popcll(b1) + __popcll(b2) + __popcll(b3);
        unsigned base = 0;
        if (lane == 0) base = atomicAdd(&cnt[rowbase + g], (unsigned)tot);
        base = (unsigned)__shfl((int)base, 0, 64);

        int c0 = __popcll(b0), c1 = c0 + __popcll(b1), c2 = c1 + __popcll(b2);
        int pos[4];
        pos[0] = __popcll(b0 & below);
        pos[1] = c0 + __popcll(b1 & below);
        pos[2] = c1 + __popcll(b2 & below);
        pos[3] = c2 + __popcll(b3 & below);

        u64* sr = surv + (size_t)(rowbase + g) * CAP;
#pragma unroll
        for (int j = 0; j < 4; ++j) {
            if (p[j]) {
                unsigned q = base + (unsigned)pos[j];
                if (q < CAP)
                    sr[q] = ((u64)__float_as_uint(d2[j]) << 32) | (unsigned)(i0 + j);
            }
        }
    }
}

// ---------------- kernel 4: exact top-9 from survivors + epilogue ----------------
#define SW(Tq) { bool c_ = x < (Tq); u64 lo_ = c_ ? x : (Tq); u64 hi_ = c_ ? (Tq) : x; (Tq) = lo_; x = hi_; }
#define SWAP9 SW(t0) SW(t1) SW(t2) SW(t3) SW(t4) SW(t5) SW(t6) SW(t7) SW(t8)

__global__ __launch_bounds__(256) void finalize_k(
    const float2* __restrict__ xy, const float* __restrict__ pred,
    const float* __restrict__ gt, const float* __restrict__ T,
    const unsigned* __restrict__ cnt, const u64* __restrict__ surv,
    float* __restrict__ out)
{
#pragma clang fp contract(off)
    const int lane = threadIdx.x & 63;
    const int wvid = threadIdx.x >> 6;
    const int row  = blockIdx.x * 4 + wvid;
    const int b = row >> 6, g = row & 63;

    const float4 gtb = ((const float4*)gt)[row];
    const float gcx = gtb.x, gcy = gtb.y;
    const float4* pred4 = (const float4*)pred + (size_t)b * NPRED;

    u64 t0=INITKEY,t1=INITKEY,t2=INITKEY,t3=INITKEY,t4=INITKEY,
        t5=INITKEY,t6=INITKEY,t7=INITKEY,t8=INITKEY;

    const unsigned n = cnt[row];
    if (n <= (unsigned)CAP) {
        const u64* sr = surv + (size_t)row * CAP;
        for (unsigned bs = 0; bs < n; bs += 64) {
            u64 cand = (bs + lane < n) ? sr[bs + lane] : INITKEY;
            u64 pend = __ballot(cand < t8);
            while (pend) {
                const int src = __ffsll(pend) - 1;
                pend &= pend - 1;
                const unsigned kd = (unsigned)__builtin_amdgcn_readlane((int)(unsigned)(cand >> 32), src);
                const unsigned ki = (unsigned)__builtin_amdgcn_readlane((int)(unsigned)cand, src);
                u64 key = ((u64)kd << 32) | ki;
                if (key < t8) {
                    u64 x = key; SWAP9;
                    pend &= __ballot(cand < t8);
                }
            }
        }
    } else {
        // overflow fallback (never on random data): exact full-row rescan
        float Tf = T[row];
        const float2* xb = xy + (size_t)b * NPRED;
        for (int k = lane; k < NPRED; k += 64) {
            float2 p = xb[k];
            float dx = __fsub_rn(gcx, p.x);
            float dy = __fsub_rn(gcy, p.y);
            float d2 = __fadd_rn(__fmul_rn(dx, dx), __fmul_rn(dy, dy));
            u64 pend = __ballot(d2 <= Tf);
            while (pend) {
                const int src = __ffsll(pend) - 1;
                pend &= pend - 1;
                const unsigned kd = (unsigned)__builtin_amdgcn_readlane((int)__float_as_uint(d2), src);
                const unsigned ki = (unsigned)(k - lane + src);
                u64 key = ((u64)kd << 32) | ki;
                if (key < t8) {
                    u64 x = key; SWAP9;
                    Tf = fminf(Tf, __uint_as_float((unsigned)(t8 >> 32)));
                    pend &= __ballot(d2 <= Tf);
                }
            }
        }
    }

    // lane k (<9) takes k-th smallest from replicated sorted list
    u64 fin = t0;
    if (lane == 1) fin = t1;
    if (lane == 2) fin = t2;
    if (lane == 3) fin = t3;
    if (lane == 4) fin = t4;
    if (lane == 5) fin = t5;
    if (lane == 6) fin = t6;
    if (lane == 7) fin = t7;
    if (lane == 8) fin = t8;

    const bool active = (lane < KCAND);
    const unsigned idx = active ? (unsigned)(fin & 0xffffffffu) : 0u;

    float4 pb = pred4[idx];

    float gx1 = gcx - 0.5f * gtb.z, gy1 = gcy - 0.5f * gtb.w;
    float gx2 = gcx + 0.5f * gtb.z, gy2 = gcy + 0.5f * gtb.w;
    float kx1 = pb.x - 0.5f * pb.z, ky1 = pb.y - 0.5f * pb.w;
    float kx2 = pb.x + 0.5f * pb.z, ky2 = pb.y + 0.5f * pb.w;

    float ltx = fmaxf(gx1, kx1), lty = fmaxf(gy1, ky1);
    float rbx = fminf(gx2, kx2), rby = fminf(gy2, ky2);
    float wvd = fmaxf(rbx - ltx, 0.0f);
    float hvd = fmaxf(rby - lty, 0.0f);
    float inter  = wvd * hvd;
    float area_a = (gx2 - gx1) * (gy2 - gy1);
    float area_b = (kx2 - kx1) * (ky2 - ky1);
    float iou = inter / ((area_a + area_b) - inter);

    float v = active ? iou : 0.0f;
    float s = v;
#pragma unroll
    for (int m = 1; m < 64; m <<= 1) s += __shfl_xor(s, m, 64);
    float mean = s / 9.0f;

    float dev = active ? (iou - mean) : 0.0f;
    float ss = dev * dev;
#pragma unroll
    for (int m = 1; m < 64; m <<= 1) ss += __shfl_xor(ss, m, 64);
    float stdv = sqrtf(ss / 8.0f);    // ddof = 1
    float thr = mean + stdv;

    bool inside = (gx1 <= pb.x) && (pb.x <= gx2) &&
                  (gy1 <= pb.y) && (pb.y <= gy2);
    bool maskk = (iou >= thr) && inside;

    if (active) {
        const size_t chunk = (size_t)BATCH * NGT * KCAND;
        const size_t o = (size_t)row * KCAND + lane;
        out[0 * chunk + o] = maskk ? (float)idx : -1.0f;
        out[1 * chunk + o] = maskk ? (float)g   : -1.0f;
        out[2 * chunk + o] = maskk ? 1.0f : 0.0f;
        out[3 * chunk + o] = iou;
    }
}

// ---------------- fallback (small ws): R4-style block-per-row two-pass ----------------
__global__ __launch_bounds__(256, 4) void atss_fb(
    const float* __restrict__ pred, const float* __restrict__ gt, float* __restrict__ out)
{
#pragma clang fp contract(off)
    const int lane = threadIdx.x & 63;
    const int wvid = threadIdx.x >> 6;
    const int b = (blockIdx.x & 7) + 8 * (blockIdx.x >> 9);
    const int g = (blockIdx.x >> 3) & 63;
    const int w = b * NGT + g;

    const float4 gtb = ((const float4*)gt)[w];
    const float gcx = gtb.x, gcy = gtb.y;
    const float4* pred4 = (const float4*)pred + (size_t)b * NPRED;

    float lmin = FINF;
    for (int k = wvid * 64 + lane; k < NPRED; k += 256) {
        float4 p = pred4[k];
        float dx = __fsub_rn(gcx, p.x);
        float dy = __fsub_rn(gcy, p.y);
        lmin = fminf(lmin, __fadd_rn(__fmul_rn(dx, dx), __fmul_rn(dy, dy)));
    }
    {
        float x = lmin;
#pragma unroll
        for (int k = 2; k <= 64; k <<= 1)
#pragma unroll
            for (int j = k >> 1; j >= 1; j >>= 1) {
                float o = __shfl_xor(x, j, 64);
                bool keepmin = (((lane & k) == 0) == ((lane & j) == 0));
                x = keepmin ? fminf(x, o) : fmaxf(x, o);
            }
        lmin = x;
    }
    float Tf = rl_f(lmin, 8);

    u64 t0=INITKEY,t1=INITKEY,t2=INITKEY,t3=INITKEY,t4=INITKEY,
        t5=INITKEY,t6=INITKEY,t7=INITKEY,t8=INITKEY;
    for (int k = wvid * 64 + lane; k < NPRED; k += 256) {
        float4 p = pred4[k];
        float dx = __fsub_rn(gcx, p.x);
        float dy = __fsub_rn(gcy, p.y);
        float d2 = __fadd_rn(__fmul_rn(dx, dx), __fmul_rn(dy, dy));
        u64 pend = __ballot(d2 <= Tf);
        while (pend) {
            const int src = __ffsll(pend) - 1;
            pend &= pend - 1;
            const unsigned kd = (unsigned)__builtin_amdgcn_readlane((int)__float_as_uint(d2), src);
            const unsigned ki = (unsigned)(k - lane + src);
            u64 key = ((u64)kd << 32) | ki;
            if (key < t8) {
                u64 x = key; SWAP9;
                Tf = fminf(Tf, __uint_as_float((unsigned)(t8 >> 32)));
                pend &= __ballot(d2 <= Tf);
            }
        }
    }

    __shared__ u64 smem[4 * KCAND];
    if (lane == 0) {
        u64* sm = smem + wvid * KCAND;
        sm[0]=t0; sm[1]=t1; sm[2]=t2; sm[3]=t3; sm[4]=t4;
        sm[5]=t5; sm[6]=t6; sm[7]=t7; sm[8]=t8;
    }
    __syncthreads();
    if (wvid != 0) return;

    u64 cand = (lane < 4 * KCAND) ? smem[lane] : INITKEY;
    t0=INITKEY;t1=INITKEY;t2=INITKEY;t3=INITKEY;t4=INITKEY;
    t5=INITKEY;t6=INITKEY;t7=INITKEY;t8=INITKEY;
    {
        u64 pend = __ballot(cand < INITKEY);
        while (pend) {
            const int src = __ffsll(pend) - 1;
            pend &= pend - 1;
            const unsigned kd = (unsigned)__builtin_amdgcn_readlane((int)(unsigned)(cand >> 32), src);
            const unsigned ki = (unsigned)__builtin_amdgcn_readlane((int)(unsigned)cand, src);
            u64 key = ((u64)kd << 32) | ki;
            if (key < t8) { u64 x = key; SWAP9; pend &= __ballot(cand < t8); }
        }
    }
    u64 fin = t0;
    if (lane == 1) fin = t1;
    if (lane == 2) fin = t2;
    if (lane == 3) fin = t3;
    if (lane == 4) fin = t4;
    if (lane == 5) fin = t5;
    if (lane == 6) fin = t6;
    if (lane == 7) fin = t7;
    if (lane == 8) fin = t8;

    const bool active = (lane < KCAND);
    const unsigned idx = active ? (unsigned)(fin & 0xffffffffu) : 0u;
    float4 pb = pred4[idx];
    float gx1 = gcx - 0.5f * gtb.z, gy1 = gcy - 0.5f * gtb.w;
    float gx2 = gcx + 0.5f * gtb.z, gy2 = gcy + 0.5f * gtb.w;
    float kx1 = pb.x - 0.5f * pb.z, ky1 = pb.y - 0.5f * pb.w;
    float kx2 = pb.x + 0.5f * pb.z, ky2 = pb.y + 0.5f * pb.w;
    float ltx = fmaxf(gx1, kx1), lty = fmaxf(gy1, ky1);
    float rbx = fminf(gx2, kx2), rby = fminf(gy2, ky2);
    float wvd = fmaxf(rbx - ltx, 0.0f), hvd = fmaxf(rby - lty, 0.0f);
    float inter  = wvd * hvd;
    float area_a = (gx2 - gx1) * (gy2 - gy1);
    float area_b = (kx2 - kx1) * (ky2 - ky1);
    float iou = inter / ((area_a + area_b) - inter);
    float v = active ? iou : 0.0f, s = v;
#pragma unroll
    for (int m = 1; m < 64; m <<= 1) s += __shfl_xor(s, m, 64);
    float mean = s / 9.0f;
    float dev = active ? (iou - mean) : 0.0f, ss = dev * dev;
#pragma unroll
    for (int m = 1; m < 64; m <<= 1) ss += __shfl_xor(ss, m, 64);
    float thr = mean + sqrtf(ss / 8.0f);
    bool inside = (gx1 <= pb.x) && (pb.x <= gx2) && (gy1 <= pb.y) && (pb.y <= gy2);
    bool maskk = (iou >= thr) && inside;
    if (active) {
        const size_t chunk = (size_t)BATCH * NGT * KCAND;
        const size_t o = (size_t)w * KCAND + lane;
        out[0 * chunk + o] = maskk ? (float)idx : -1.0f;
        out[1 * chunk + o] = maskk ? (float)g   : -1.0f;
        out[2 * chunk + o] = maskk ? 1.0f : 0.0f;
        out[3 * chunk + o] = iou;
    }
}
#undef SWAP9
#undef SW

extern "C" void kernel_launch(void* const* d_in, const int* in_sizes, int n_in,
                              void* d_out, int out_size, void* d_ws, size_t ws_size,
                              hipStream_t stream) {
    const float* pred = (const float*)d_in[0];   // [16, 30000, 4] f32
    const float* gtb  = (const float*)d_in[1];   // [16, 64, 4] f32
    float* out = (float*)d_out;

    // ws layout
    const size_t off_xy   = 0;
    const size_t off_sub  = off_xy  + (size_t)BATCH * NPRED * sizeof(float2);  // 3.84 MB
    const size_t off_T    = off_sub + (size_t)BATCH * SUBN  * sizeof(float2);  // +480 KB
    const size_t off_cnt  = off_T   + (size_t)BATCH * NGT * sizeof(float);     // +4 KB
    const size_t off_surv = off_cnt + (size_t)BATCH * NGT * sizeof(unsigned);  // +4 KB
    const size_t need     = off_surv + (size_t)BATCH * NGT * CAP * sizeof(u64);// +8 MB

    if (ws_size >= need) {
        char* ws = (char*)d_ws;
        float2*   xy   = (float2*)(ws + off_xy);
        float2*   sub  = (float2*)(ws + off_sub);
        float*    T    = (float*)(ws + off_T);
        unsigned* cnt  = (unsigned*)(ws + off_cnt);
        u64*      surv = (u64*)(ws + off_surv);

        compact_k<<<(BATCH * NPRED + 255) / 256, 256, 0, stream>>>(pred, xy, sub);
        hipMemsetAsync(cnt, 0, (size_t)BATCH * NGT * sizeof(unsigned), stream);
        thresh_k<<<BATCH * NGT / 4, 256, 0, stream>>>(sub, gtb, T);
        collect_k<<<BATCH * NCH, 256, 0, stream>>>(xy, gtb, T, cnt, surv);
        finalize_k<<<BATCH * NGT / 4, 256, 0, stream>>>(xy, pred, gtb, T, cnt, surv, out);
    } else {
        atss_fb<<<BATCH * NGT, 256, 0, stream>>>(pred, gtb, out);
    }
}

// Round 9
// 97.827 us; speedup vs baseline: 1.5198x; 1.5198x over previous
//
#include <hip/hip_runtime.h>
#include <stdint.h>

typedef unsigned long long u64;

#define KCAND 9
#define BATCH 16
#define NPRED 30000
#define NPAD  30720          // 15 * 2048, padded with +inf
#define NGT   64
#define NT    15
#define TILEF2 2048          // float2 elements per tile (16 KB)
#define INITKEY 0x7F800000FFFFFFFFULL
#define FINF __uint_as_float(0x7F800000u)

__device__ __forceinline__ float rl_f(float v, int l) {
    return __uint_as_float((unsigned)__builtin_amdgcn_readlane((int)__float_as_uint(v), l));
}

// ---------- kernel 1: compact xy to [B][NPAD] float2, pad = +inf ----------
__global__ __launch_bounds__(256) void compact_k(
    const float* __restrict__ pred, float2* __restrict__ xyp)
{
    int e = blockIdx.x * 256 + threadIdx.x;
    if (e >= BATCH * NPAD) return;
    int b = e / NPAD;
    int i = e - b * NPAD;
    float2 v = make_float2(FINF, FINF);
    if (i < NPRED) {
        float4 p = ((const float4*)pred)[b * NPRED + i];
        v = make_float2(p.x, p.y);
    }
    xyp[e] = v;
}

#define SW(Tq) { bool c_ = x < (Tq); u64 lo_ = c_ ? x : (Tq); u64 hi_ = c_ ? (Tq) : x; (Tq) = lo_; x = hi_; }
#define SWAP9 SW(t0) SW(t1) SW(t2) SW(t3) SW(t4) SW(t5) SW(t6) SW(t7) SW(t8)

// ---------- kernel 2: 2 rows/block, LDS-tiled, 2 waves per row ----------
__global__ __launch_bounds__(256, 2) void atss_k(
    const float2* __restrict__ xyp, const float* __restrict__ pred,
    const float* __restrict__ gt, float* __restrict__ out)
{
#pragma clang fp contract(off)
    const int tid  = threadIdx.x;
    const int lane = tid & 63;
    const int wv   = tid >> 6;
    // blockIdx = pairi*16 + b  -> image b sits on XCD b%8 (L2-resident slice)
    const int b     = blockIdx.x & 15;
    const int pairi = blockIdx.x >> 4;       // 0..31
    const int rloc  = wv >> 1;               // which of the block's 2 rows
    const int par   = wv & 1;                // tile-group parity this wave scans
    const int row   = b * NGT + pairi * 2 + rloc;
    const int g     = row & 63;

    __shared__ float2 tile[2][TILEF2];       // 32 KB double buffer
    __shared__ u64 mbuf[2][KCAND];

    const float4 gtb = ((const float4*)gt)[row];
    const float gcx = gtb.x, gcy = gtb.y;
    const float4* xb4   = (const float4*)(xyp + (size_t)b * NPAD);  // NPAD/2=15360 float4
    const float4* pred4 = (const float4*)pred + (size_t)b * NPRED;

    // staging registers: this thread stages float4 slots tid+{0,256,512,768}
    // of each 1024-float4 tile  (BUGFIX vs R7: full tile, not half)
    float4 r0 = xb4[tid], r1 = xb4[tid + 256], r2 = xb4[tid + 512], r3 = xb4[tid + 768];

    u64 t0=INITKEY,t1=INITKEY,t2=INITKEY,t3=INITKEY,t4=INITKEY,
        t5=INITKEY,t6=INITKEY,t7=INITKEY,t8=INITKEY;
    const float INFL = 1.0f + 9.5367431640625e-7f;   // 1 + 2^-20
    float Tf = FINF;                                  // inflated running threshold

    for (int t = 0; t < NT; ++t) {
        float4* dstb = (float4*)tile[t & 1];
        dstb[tid]       = r0;
        dstb[tid + 256] = r1;
        dstb[tid + 512] = r2;
        dstb[tid + 768] = r3;
        __syncthreads();                      // tile t visible to all waves
        if (t + 1 < NT) {                     // prefetch next tile (overlaps processing)
            const int nb = (t + 1) * 1024 + tid;
            r0 = xb4[nb];
            r1 = xb4[nb + 256];
            r2 = xb4[nb + 512];
            r3 = xb4[nb + 768];
        }
        const float2* tl = tile[t & 1];

        if (t == 0) {
            // bootstrap: T1 = 9th-smallest of 64 lane-mins over my tile-0 slice.
            // The 9 smallest lane-mins are 9 distinct elements => T1 >= slice's
            // 9th-smallest fast-d2 >= (1-2^-22) * subset's exact d9; *(1+2^-20)
            // inflation keeps the filter conservative vs exact keys.
            float lmin = FINF;
#pragma unroll
            for (int gg = 0; gg < 2; ++gg) {
                const int base = (par + gg * 2) * 512;
#pragma unroll
                for (int j = 0; j < 8; ++j) {
                    float2 p = tl[base + j * 64 + lane];
                    float dx = gcx - p.x, dy = gcy - p.y;
                    lmin = fminf(lmin, __builtin_fmaf(dy, dy, dx * dx));
                }
            }
            float x = lmin;
#pragma unroll
            for (int k = 2; k <= 64; k <<= 1)
#pragma unroll
                for (int j = k >> 1; j >= 1; j >>= 1) {
                    float o = __shfl_xor(x, j, 64);
                    bool keepmin = (((lane & k) == 0) == ((lane & j) == 0));
                    x = keepmin ? fminf(x, o) : fmaxf(x, o);
                }
            Tf = rl_f(x, 8) * INFL;
        }

#pragma unroll
        for (int gg = 0; gg < 2; ++gg) {
            const int base = (par + gg * 2) * 512;
            float fx[8], fy[8], d2[8];
#pragma unroll
            for (int j = 0; j < 8; ++j) {
                float2 p = tl[base + j * 64 + lane];
                fx[j] = p.x; fy[j] = p.y;
                float dx = gcx - p.x, dy = gcy - p.y;
                d2[j] = __builtin_fmaf(dy, dy, dx * dx);   // fast metric (filter only)
            }
            float dmin = d2[0];
#pragma unroll
            for (int j = 1; j < 8; ++j) dmin = fminf(dmin, d2[j]);
            if (__ballot(dmin <= Tf) == 0ULL) continue;
#pragma unroll
            for (int j = 0; j < 8; ++j) {
                u64 pend = __ballot(d2[j] <= Tf);
                while (pend) {
                    const int src = __ffsll(pend) - 1;
                    pend &= pend - 1;
                    float ex = rl_f(fx[j], src);
                    float ey = rl_f(fy[j], src);
                    float dxe = __fsub_rn(gcx, ex);
                    float dye = __fsub_rn(gcy, ey);
                    float de  = __fadd_rn(__fmul_rn(dxe, dxe), __fmul_rn(dye, dye));
                    const unsigned idx = (unsigned)(t * TILEF2 + base + j * 64 + src);
                    u64 key = ((u64)__float_as_uint(de) << 32) | idx;   // exact (d2, idx)
                    if (key < t8) {
                        u64 x = key; SWAP9;
                        Tf = fminf(Tf, __uint_as_float((unsigned)(t8 >> 32)) * INFL);
                        pend &= __ballot(d2[j] <= Tf);
                    }
                }
            }
        }
    }

    // per-lane pick from my replicated sorted list
    u64 myk = t0;
    if (lane == 1) myk = t1;
    if (lane == 2) myk = t2;
    if (lane == 3) myk = t3;
    if (lane == 4) myk = t4;
    if (lane == 5) myk = t5;
    if (lane == 6) myk = t6;
    if (lane == 7) myk = t7;
    if (lane == 8) myk = t8;

    if (par == 1 && lane < KCAND) mbuf[rloc][lane] = myk;
    __syncthreads();
    if (par == 1) return;

    // merge partner wave's 9 keys (exact u64 event loop)
    {
        u64 cand = (lane < KCAND) ? mbuf[rloc][lane] : INITKEY;
        u64 pend = __ballot(cand < t8);
        while (pend) {
            const int src = __ffsll(pend) - 1;
            pend &= pend - 1;
            const unsigned kd = (unsigned)__builtin_amdgcn_readlane((int)(unsigned)(cand >> 32), src);
            const unsigned ki = (unsigned)__builtin_amdgcn_readlane((int)(unsigned)cand, src);
            u64 key = ((u64)kd << 32) | ki;
            if (key < t8) {
                u64 x = key; SWAP9;
                pend &= __ballot(cand < t8);
            }
        }
    }

    u64 fin = t0;
    if (lane == 1) fin = t1;
    if (lane == 2) fin = t2;
    if (lane == 3) fin = t3;
    if (lane == 4) fin = t4;
    if (lane == 5) fin = t5;
    if (lane == 6) fin = t6;
    if (lane == 7) fin = t7;
    if (lane == 8) fin = t8;

    // ---------- epilogue (unchanged, absmax-0 proven) ----------
    const bool active = (lane < KCAND);
    const unsigned idx = active ? (unsigned)(fin & 0xffffffffu) : 0u;

    float4 pb = pred4[idx];

    float gx1 = gcx - 0.5f * gtb.z, gy1 = gcy - 0.5f * gtb.w;
    float gx2 = gcx + 0.5f * gtb.z, gy2 = gcy + 0.5f * gtb.w;
    float kx1 = pb.x - 0.5f * pb.z, ky1 = pb.y - 0.5f * pb.w;
    float kx2 = pb.x + 0.5f * pb.z, ky2 = pb.y + 0.5f * pb.w;

    float ltx = fmaxf(gx1, kx1), lty = fmaxf(gy1, ky1);
    float rbx = fminf(gx2, kx2), rby = fminf(gy2, ky2);
    float wvd = fmaxf(rbx - ltx, 0.0f);
    float hvd = fmaxf(rby - lty, 0.0f);
    float inter  = wvd * hvd;
    float area_a = (gx2 - gx1) * (gy2 - gy1);
    float area_b = (kx2 - kx1) * (ky2 - ky1);
    float iou = inter / ((area_a + area_b) - inter);

    float v = active ? iou : 0.0f;
    float s = v;
#pragma unroll
    for (int m = 1; m < 64; m <<= 1) s += __shfl_xor(s, m, 64);
    float mean = s / 9.0f;

    float dev = active ? (iou - mean) : 0.0f;
    float ss = dev * dev;
#pragma unroll
    for (int m = 1; m < 64; m <<= 1) ss += __shfl_xor(ss, m, 64);
    float stdv = sqrtf(ss / 8.0f);    // ddof = 1
    float thr = mean + stdv;

    bool inside = (gx1 <= pb.x) && (pb.x <= gx2) &&
                  (gy1 <= pb.y) && (pb.y <= gy2);
    bool maskk = (iou >= thr) && inside;

    if (active) {
        const size_t chunk = (size_t)BATCH * NGT * KCAND;
        const size_t o = (size_t)row * KCAND + lane;
        out[0 * chunk + o] = maskk ? (float)idx : -1.0f;
        out[1 * chunk + o] = maskk ? (float)g   : -1.0f;
        out[2 * chunk + o] = maskk ? 1.0f : 0.0f;
        out[3 * chunk + o] = iou;
    }
}

// ---------- fallback (small ws): proven block-per-row two-pass ----------
__global__ __launch_bounds__(256, 4) void atss_fb(
    const float* __restrict__ pred, const float* __restrict__ gt, float* __restrict__ out)
{
#pragma clang fp contract(off)
    const int lane = threadIdx.x & 63;
    const int wvid = threadIdx.x >> 6;
    const int b = (blockIdx.x & 7) + 8 * (blockIdx.x >> 9);
    const int g = (blockIdx.x >> 3) & 63;
    const int w = b * NGT + g;

    const float4 gtb = ((const float4*)gt)[w];
    const float gcx = gtb.x, gcy = gtb.y;
    const float4* pred4 = (const float4*)pred + (size_t)b * NPRED;

    float lmin = FINF;
    for (int k = wvid * 64 + lane; k < NPRED; k += 256) {
        float4 p = pred4[k];
        float dx = __fsub_rn(gcx, p.x);
        float dy = __fsub_rn(gcy, p.y);
        lmin = fminf(lmin, __fadd_rn(__fmul_rn(dx, dx), __fmul_rn(dy, dy)));
    }
    {
        float x = lmin;
#pragma unroll
        for (int k = 2; k <= 64; k <<= 1)
#pragma unroll
            for (int j = k >> 1; j >= 1; j >>= 1) {
                float o = __shfl_xor(x, j, 64);
                bool keepmin = (((lane & k) == 0) == ((lane & j) == 0));
                x = keepmin ? fminf(x, o) : fmaxf(x, o);
            }
        lmin = x;
    }
    float Tf = rl_f(lmin, 8);

    u64 t0=INITKEY,t1=INITKEY,t2=INITKEY,t3=INITKEY,t4=INITKEY,
        t5=INITKEY,t6=INITKEY,t7=INITKEY,t8=INITKEY;
    for (int k = wvid * 64 + lane; k < NPRED; k += 256) {
        float4 p = pred4[k];
        float dx = __fsub_rn(gcx, p.x);
        float dy = __fsub_rn(gcy, p.y);
        float d2 = __fadd_rn(__fmul_rn(dx, dx), __fmul_rn(dy, dy));
        u64 pend = __ballot(d2 <= Tf);
        while (pend) {
            const int src = __ffsll(pend) - 1;
            pend &= pend - 1;
            const unsigned kd = (unsigned)__builtin_amdgcn_readlane((int)__float_as_uint(d2), src);
            const unsigned ki = (unsigned)(k - lane + src);
            u64 key = ((u64)kd << 32) | ki;
            if (key < t8) {
                u64 x = key; SWAP9;
                Tf = fminf(Tf, __uint_as_float((unsigned)(t8 >> 32)));
                pend &= __ballot(d2 <= Tf);
            }
        }
    }

    __shared__ u64 smem[4 * KCAND];
    if (lane == 0) {
        u64* sm = smem + wvid * KCAND;
        sm[0]=t0; sm[1]=t1; sm[2]=t2; sm[3]=t3; sm[4]=t4;
        sm[5]=t5; sm[6]=t6; sm[7]=t7; sm[8]=t8;
    }
    __syncthreads();
    if (wvid != 0) return;

    u64 cand = (lane < 4 * KCAND) ? smem[lane] : INITKEY;
    t0=INITKEY;t1=INITKEY;t2=INITKEY;t3=INITKEY;t4=INITKEY;
    t5=INITKEY;t6=INITKEY;t7=INITKEY;t8=INITKEY;
    {
        u64 pend = __ballot(cand < INITKEY);
        while (pend) {
            const int src = __ffsll(pend) - 1;
            pend &= pend - 1;
            const unsigned kd = (unsigned)__builtin_amdgcn_readlane((int)(unsigned)(cand >> 32), src);
            const unsigned ki = (unsigned)__builtin_amdgcn_readlane((int)(unsigned)cand, src);
            u64 key = ((u64)kd << 32) | ki;
            if (key < t8) { u64 x = key; SWAP9; pend &= __ballot(cand < t8); }
        }
    }
    u64 fin = t0;
    if (lane == 1) fin = t1;
    if (lane == 2) fin = t2;
    if (lane == 3) fin = t3;
    if (lane == 4) fin = t4;
    if (lane == 5) fin = t5;
    if (lane == 6) fin = t6;
    if (lane == 7) fin = t7;
    if (lane == 8) fin = t8;

    const bool active = (lane < KCAND);
    const unsigned idx = active ? (unsigned)(fin & 0xffffffffu) : 0u;
    float4 pb = pred4[idx];
    float gx1 = gcx - 0.5f * gtb.z, gy1 = gcy - 0.5f * gtb.w;
    float gx2 = gcx + 0.5f * gtb.z, gy2 = gcy + 0.5f * gtb.w;
    float kx1 = pb.x - 0.5f * pb.z, ky1 = pb.y - 0.5f * pb.w;
    float kx2 = pb.x + 0.5f * pb.z, ky2 = pb.y + 0.5f * pb.w;
    float ltx = fmaxf(gx1, kx1), lty = fmaxf(gy1, ky1);
    float rbx = fminf(gx2, kx2), rby = fminf(gy2, ky2);
    float wvd = fmaxf(rbx - ltx, 0.0f), hvd = fmaxf(rby - lty, 0.0f);
    float inter  = wvd * hvd;
    float area_a = (gx2 - gx1) * (gy2 - gy1);
    float area_b = (kx2 - kx1) * (ky2 - ky1);
    float iou = inter / ((area_a + area_b) - inter);
    float v = active ? iou : 0.0f, s = v;
#pragma unroll
    for (int m = 1; m < 64; m <<= 1) s += __shfl_xor(s, m, 64);
    float mean = s / 9.0f;
    float dev = active ? (iou - mean) : 0.0f, ss = dev * dev;
#pragma unroll
    for (int m = 1; m < 64; m <<= 1) ss += __shfl_xor(ss, m, 64);
    float thr = mean + sqrtf(ss / 8.0f);
    bool inside = (gx1 <= pb.x) && (pb.x <= gx2) && (gy1 <= pb.y) && (pb.y <= gy2);
    bool maskk = (iou >= thr) && inside;
    if (active) {
        const size_t chunk = (size_t)BATCH * NGT * KCAND;
        const size_t o = (size_t)w * KCAND + lane;
        out[0 * chunk + o] = maskk ? (float)idx : -1.0f;
        out[1 * chunk + o] = maskk ? (float)g   : -1.0f;
        out[2 * chunk + o] = maskk ? 1.0f : 0.0f;
        out[3 * chunk + o] = iou;
    }
}
#undef SWAP9
#undef SW

extern "C" void kernel_launch(void* const* d_in, const int* in_sizes, int n_in,
                              void* d_out, int out_size, void* d_ws, size_t ws_size,
                              hipStream_t stream) {
    const float* pred = (const float*)d_in[0];   // [16, 30000, 4] f32
    const float* gtb  = (const float*)d_in[1];   // [16, 64, 4] f32
    float* out = (float*)d_out;

    const size_t need = (size_t)BATCH * NPAD * sizeof(float2);   // ~3.93 MB
    if (ws_size >= need) {
        float2* xyp = (float2*)d_ws;
        compact_k<<<(BATCH * NPAD) / 256, 256, 0, stream>>>(pred, xyp);
        // 512 blocks = 32 row-pairs x 16 images; image b -> XCD b%8
        atss_k<<<BATCH * NGT / 2, 256, 0, stream>>>(xyp, pred, gtb, out);
    } else {
        atss_fb<<<BATCH * NGT, 256, 0, stream>>>(pred, gtb, out);
    }
}